// Round 3
// baseline (453.501 us; speedup 1.0000x reference)
//
#include <hip/hip_runtime.h>

#define T_TOK 4096
#define H_DIM 512
#define I_DIM 1024
#define E_NUM 32
#define KTOP  2
#define CAP   512
#define NROWS (E_NUM * CAP)    // 16384
#define NPAIR (T_TOK * KTOP)   // 8192

typedef __attribute__((ext_vector_type(8))) short short8;    // 8 bf16 = 4 VGPRs
typedef __attribute__((ext_vector_type(4))) float float4v;
typedef __attribute__((ext_vector_type(4))) unsigned int uint4v;

// round-half-up bf16 (differs from RNE only on exact ties; inputs are finite)
__device__ __forceinline__ unsigned int pack_rn(float a, float b) {
  unsigned int ua = __float_as_uint(a) + 0x8000u;
  unsigned int ub = __float_as_uint(b) + 0x8000u;
  return (ua >> 16) | (ub & 0xffff0000u);  // compiler folds to v_perm-class ops
}
__device__ __forceinline__ unsigned short f2bf_rn(float f) {
  return (unsigned short)((__float_as_uint(f) + 0x8000u) >> 16);
}
__device__ __forceinline__ float bf2f(unsigned short s) {
  return __uint_as_float(((unsigned int)s) << 16);
}
__device__ __forceinline__ short8 cvt8(float4v f0, float4v f1) {
  union { uint4v u; short8 s; } r;
  r.u.x = pack_rn(f0.x, f0.y);
  r.u.y = pack_rn(f0.z, f0.w);
  r.u.z = pack_rn(f1.x, f1.y);
  r.u.w = pack_rn(f1.z, f1.w);
  return r.s;
}

// ---------------- routing ----------------
__global__ void k_route(const int* __restrict__ idx, int* __restrict__ counts,
                        int* __restrict__ slot_token, int* __restrict__ inv) {
  int i = blockIdx.x * 256 + threadIdx.x;
  if (i >= NPAIR) return;
  int e = idx[i];
  int p = atomicAdd(counts + e, 1);
  if (p < CAP) {
    slot_token[e * CAP + p] = i >> 1;  // KTOP == 2
    inv[i] = e * CAP + p;
  } else {
    inv[i] = -1;
  }
}

// ---------------- gather tokens -> bf16 dispatch buffer (zero-pad to 128) ----
__global__ void k_gather(const float* __restrict__ hs, const int* __restrict__ counts,
                         const int* __restrict__ slot_token, unsigned short* __restrict__ xd) {
  const int r = blockIdx.x * 4 + (threadIdx.x >> 6);  // one wave per row
  const int lane = threadIdx.x & 63;
  const int e = r >> 9;
  const int p = r & (CAP - 1);
  const int cnt = min(counts[e], CAP);
  if (p >= ((cnt + 127) & ~127)) return;  // beyond last padded tile: never read
  uint4v v = {0u, 0u, 0u, 0u};
  if (p < cnt) {
    const int t = slot_token[r];
    const float4v* src = (const float4v*)(hs + (size_t)t * H_DIM);
    float4v f0 = src[lane * 2];
    float4v f1 = src[lane * 2 + 1];
    v.x = pack_rn(f0.x, f0.y);
    v.y = pack_rn(f0.z, f0.w);
    v.z = pack_rn(f1.x, f1.y);
    v.w = pack_rn(f1.z, f1.w);
  }
  *(uint4v*)(xd + (size_t)r * H_DIM + lane * 8) = v;
}

// ---------------- GEMM1 (LDS-free K-loop): per-wave 64x64 tile, direct global->reg frags ----
// Block = 64 rows x 128 cols; waves 0,1 = gate cols, waves 2,3 = matching up cols.
// Single barrier at epilogue to exchange `u` through LDS for the silu fuse.
__global__ __launch_bounds__(256, 2) void k_gemm1(const unsigned short* __restrict__ xd,
                                                  const float* __restrict__ gup,
                                                  const int* __restrict__ counts,
                                                  unsigned short* __restrict__ act) {
  __shared__ float lds_u[2][64 * 65];  // +1 pad: row stride 65 breaks bank aliasing

  const int rbase = blockIdx.y * 64;
  const int e = rbase >> 9;
  const int cnt = min(counts[e], CAP);
  if ((rbase & (CAP - 1)) >= cnt) return;  // block-uniform: no barrier divergence

  const int tid = threadIdx.x;
  const int lane = tid & 63;
  const int w = tid >> 6;
  const int sub = w & 1;
  const int isUp = w >> 1;
  const int ml = lane & 15, kg = lane >> 4;

  const float* bp = gup + (size_t)e * (2 * I_DIM * H_DIM)
                  + (size_t)(isUp * I_DIM + blockIdx.x * 128 + sub * 64 + ml) * H_DIM + kg * 8;
  const unsigned short* ap = xd + (size_t)(rbase + ml) * H_DIM + kg * 8;

  float4v acc[4][4] = {};
  short8 aC[4], aN[4];
  float4v bC[4][2], bN[4][2];

#pragma unroll
  for (int mi = 0; mi < 4; ++mi) aC[mi] = *(const short8*)(ap + mi * 16 * H_DIM);
#pragma unroll
  for (int ni = 0; ni < 4; ++ni) {
    bC[ni][0] = *(const float4v*)(bp + (size_t)ni * 16 * H_DIM);
    bC[ni][1] = *(const float4v*)(bp + (size_t)ni * 16 * H_DIM + 4);
  }

  for (int kk = 0; kk < H_DIM; kk += 32) {
    const int kn = kk + 32;
    if (kn < H_DIM) {  // prefetch next k-step while MFMA runs on current
#pragma unroll
      for (int mi = 0; mi < 4; ++mi) aN[mi] = *(const short8*)(ap + mi * 16 * H_DIM + kn);
#pragma unroll
      for (int ni = 0; ni < 4; ++ni) {
        bN[ni][0] = *(const float4v*)(bp + (size_t)ni * 16 * H_DIM + kn);
        bN[ni][1] = *(const float4v*)(bp + (size_t)ni * 16 * H_DIM + kn + 4);
      }
    }
    short8 bf[4];
#pragma unroll
    for (int ni = 0; ni < 4; ++ni) bf[ni] = cvt8(bC[ni][0], bC[ni][1]);
#pragma unroll
    for (int mi = 0; mi < 4; ++mi)
#pragma unroll
      for (int ni = 0; ni < 4; ++ni)
        acc[mi][ni] = __builtin_amdgcn_mfma_f32_16x16x32_bf16(aC[mi], bf[ni], acc[mi][ni], 0, 0, 0);
#pragma unroll
    for (int mi = 0; mi < 4; ++mi) aC[mi] = aN[mi];
#pragma unroll
    for (int ni = 0; ni < 4; ++ni) { bC[ni][0] = bN[ni][0]; bC[ni][1] = bN[ni][1]; }
  }

  if (isUp) {
    float* dst = lds_u[sub];
#pragma unroll
    for (int mi = 0; mi < 4; ++mi)
#pragma unroll
      for (int ni = 0; ni < 4; ++ni)
#pragma unroll
        for (int rg = 0; rg < 4; ++rg)
          dst[(mi * 16 + kg * 4 + rg) * 65 + ni * 16 + ml] = acc[mi][ni][rg];
  }
  __syncthreads();
  if (!isUp) {
    const float* usrc = lds_u[sub];
    unsigned short* ao = act + (size_t)rbase * I_DIM + blockIdx.x * 128 + sub * 64;
#pragma unroll
    for (int mi = 0; mi < 4; ++mi)
#pragma unroll
      for (int rg = 0; rg < 4; ++rg) {
        int row = mi * 16 + kg * 4 + rg;
#pragma unroll
        for (int ni = 0; ni < 4; ++ni) {
          float g = acc[mi][ni][rg];
          float u = usrc[row * 65 + ni * 16 + ml];
          float a = (g / (1.0f + __expf(-g))) * u;
          ao[(size_t)row * I_DIM + ni * 16 + ml] = f2bf_rn(a);
        }
      }
  }
}

// ---------------- GEMM2 (LDS-free, barrier-free): per-wave 64x64, yd bf16 out ----
__global__ __launch_bounds__(256, 2) void k_gemm2(const unsigned short* __restrict__ act,
                                                  const float* __restrict__ dwn,
                                                  const int* __restrict__ counts,
                                                  unsigned short* __restrict__ yd) {
  const int rbase = blockIdx.y * 64;
  const int e = rbase >> 9;
  const int cnt = min(counts[e], CAP);
  if ((rbase & (CAP - 1)) >= cnt) return;

  const int tid = threadIdx.x;
  const int lane = tid & 63;
  const int w = tid >> 6;
  const int ml = lane & 15, kg = lane >> 4;
  const int col0 = blockIdx.x * 256 + w * 64;

  const float* bp = dwn + (size_t)e * (H_DIM * I_DIM) + (size_t)(col0 + ml) * I_DIM + kg * 8;
  const unsigned short* ap = act + (size_t)(rbase + ml) * I_DIM + kg * 8;

  float4v acc[4][4] = {};
  short8 aC[4], aN[4];
  float4v bC[4][2], bN[4][2];

#pragma unroll
  for (int mi = 0; mi < 4; ++mi) aC[mi] = *(const short8*)(ap + mi * 16 * I_DIM);
#pragma unroll
  for (int ni = 0; ni < 4; ++ni) {
    bC[ni][0] = *(const float4v*)(bp + (size_t)ni * 16 * I_DIM);
    bC[ni][1] = *(const float4v*)(bp + (size_t)ni * 16 * I_DIM + 4);
  }

  for (int kk = 0; kk < I_DIM; kk += 32) {
    const int kn = kk + 32;
    if (kn < I_DIM) {
#pragma unroll
      for (int mi = 0; mi < 4; ++mi) aN[mi] = *(const short8*)(ap + mi * 16 * I_DIM + kn);
#pragma unroll
      for (int ni = 0; ni < 4; ++ni) {
        bN[ni][0] = *(const float4v*)(bp + (size_t)ni * 16 * I_DIM + kn);
        bN[ni][1] = *(const float4v*)(bp + (size_t)ni * 16 * I_DIM + kn + 4);
      }
    }
    short8 bf[4];
#pragma unroll
    for (int ni = 0; ni < 4; ++ni) bf[ni] = cvt8(bC[ni][0], bC[ni][1]);
#pragma unroll
    for (int mi = 0; mi < 4; ++mi)
#pragma unroll
      for (int ni = 0; ni < 4; ++ni)
        acc[mi][ni] = __builtin_amdgcn_mfma_f32_16x16x32_bf16(aC[mi], bf[ni], acc[mi][ni], 0, 0, 0);
#pragma unroll
    for (int mi = 0; mi < 4; ++mi) aC[mi] = aN[mi];
#pragma unroll
    for (int ni = 0; ni < 4; ++ni) { bC[ni][0] = bN[ni][0]; bC[ni][1] = bN[ni][1]; }
  }

  unsigned short* yo = yd + (size_t)rbase * H_DIM + col0;
#pragma unroll
  for (int mi = 0; mi < 4; ++mi)
#pragma unroll
    for (int rg = 0; rg < 4; ++rg) {
      int row = mi * 16 + kg * 4 + rg;
#pragma unroll
      for (int ni = 0; ni < 4; ++ni)
        yo[(size_t)row * H_DIM + ni * 16 + ml] = f2bf_rn(acc[mi][ni][rg]);
    }
}

// ---------------- combine: out[t] = sum_k w[t,k] * yd[inv[t,k]] ----------------
__global__ void k_combine(const unsigned short* __restrict__ yd, const int* __restrict__ inv,
                          const float* __restrict__ wts, float* __restrict__ out) {
  const int t = blockIdx.x * 4 + (threadIdx.x >> 6);  // one wave per token
  const int lane = threadIdx.x & 63;
  const int i0 = 2 * t, i1 = 2 * t + 1;
  const int r0 = inv[i0], r1 = inv[i1];
  float o[8] = {0.f, 0.f, 0.f, 0.f, 0.f, 0.f, 0.f, 0.f};
  if (r0 >= 0) {
    float w = wts[i0];
    short8 y = *(const short8*)(yd + (size_t)r0 * H_DIM + lane * 8);
#pragma unroll
    for (int j = 0; j < 8; ++j) o[j] += w * bf2f((unsigned short)y[j]);
  }
  if (r1 >= 0) {
    float w = wts[i1];
    short8 y = *(const short8*)(yd + (size_t)r1 * H_DIM + lane * 8);
#pragma unroll
    for (int j = 0; j < 8; ++j) o[j] += w * bf2f((unsigned short)y[j]);
  }
  float4v v0 = {o[0], o[1], o[2], o[3]};
  float4v v1 = {o[4], o[5], o[6], o[7]};
  float4v* dst = (float4v*)(out + (size_t)t * H_DIM + lane * 8);
  dst[0] = v0;
  dst[1] = v1;
}

extern "C" void kernel_launch(void* const* d_in, const int* in_sizes, int n_in,
                              void* d_out, int out_size, void* d_ws, size_t ws_size,
                              hipStream_t stream) {
  const float* hs  = (const float*)d_in[0];  // [T,H]
  const int*   idx = (const int*)d_in[1];    // [T,K]
  const float* wts = (const float*)d_in[2];  // [T,K]
  const float* gup = (const float*)d_in[3];  // [E,2I,H]
  const float* dwn = (const float*)d_in[4];  // [E,H,I]
  float* out = (float*)d_out;                // [T,H]

  char* ws = (char*)d_ws;
  int* counts       = (int*)ws;                             // 128 B used
  int* inv          = (int*)(ws + 1024);                    // 32 KB
  int* slot_token   = (int*)(ws + 1024 + 32768);            // 64 KB
  unsigned short* xd  = (unsigned short*)(ws + 131072);     // 16 MB
  unsigned short* act = xd + (size_t)NROWS * H_DIM;         // 33.5 MB
  unsigned short* yd  = xd;  // xd dead after gemm1; alias (16 MB)

  hipMemsetAsync(counts, 0, E_NUM * sizeof(int), stream);
  k_route<<<NPAIR / 256, 256, 0, stream>>>(idx, counts, slot_token, inv);
  k_gather<<<NROWS / 4, 256, 0, stream>>>(hs, counts, slot_token, xd);
  dim3 g1(I_DIM / 128, NROWS / 64);   // 8 x 256
  k_gemm1<<<g1, 256, 0, stream>>>(xd, gup, counts, act);
  dim3 g2(H_DIM / 256, NROWS / 64);   // 2 x 256
  k_gemm2<<<g2, 256, 0, stream>>>(act, dwn, counts, yd);
  k_combine<<<T_TOK / 4, 256, 0, stream>>>(yd, inv, wts, out);
}